// Round 11
// baseline (546.331 us; speedup 1.0000x reference)
//
#include <hip/hip_runtime.h>

typedef __bf16 bf16_t;
typedef __bf16 bf16x8v __attribute__((ext_vector_type(8)));
typedef float f32x4 __attribute__((ext_vector_type(4)));

#define CB 4
#define CE 768
#define CH 12
#define CD 64

// native v_exp_f32 (exp2) without touching libm (glibc macro clash with __exp2f)
__device__ __forceinline__ float fexp2(float x) { return __builtin_amdgcn_exp2f(x); }

// async global->LDS, 16B per lane; dest = wave-uniform base + lane*16 (linear)
__device__ __forceinline__ void gload16(const void* g, void* l) {
    __builtin_amdgcn_global_load_lds((const __attribute__((address_space(1))) void*)g,
                                     (__attribute__((address_space(3))) void*)l, 16, 0, 0);
}

// bijective XCD-aware remap: XCD x computes a contiguous slab of tiles
__device__ __forceinline__ void xcd_remap(int& bx, int& by, int gx, int gy) {
    int nwg = gx * gy;
    if ((nwg & 7) == 0) {
        int lin = by * gx + bx;
        int lin2 = (lin & 7) * (nwg >> 3) + (lin >> 3);
        bx = lin2 % gx;
        by = lin2 / gx;
    }
}

// ===== MFMA GEMM, B pre-transposed [N,K] bf16, BK=64 =====
// STATIC double-buffer (As0/As1,Bs0/Bs1) + global_load_lds.
// Tile policy: 128x64 (48KB LDS, 3 blocks/CU) big GEMMs; 64x64 (32KB, 5/CU) small.
// LDS slot swizzle: physical 16B-slot p of row r holds logical slot p ^ (r&7).
// CONCAT: kk<768 -> A0, kk>=768 -> A1. ACT: 0 none,1 sigmoid,2 gelu.
// RES: 0 none, 2 += f32 resid. OUT: 0 bf16, 1 f32, 2 f32->C + bf16->C2.
// CMODE: 0 normal(ldc); 2 split [b,H,s,d]; 4 qkv->C,C2,C3; 5 kv: k->C, v->C2^T;
//        6 dual-gate (N-stacked); 7 gate-blend: C = g*C2 + (1-g)*C3;
//        9 mem: k->C=mkt [h,slot,d], v->C2=mvt [h,d,slot], zero slots>=100.
template<int BM, int BN, int CONCAT, int ACT, int RES, int OUT, int CMODE>
__global__ __launch_bounds__(256)
void gemm_n(const bf16_t* __restrict__ A0, const bf16_t* __restrict__ A1,
            const bf16_t* __restrict__ Bt, const float* __restrict__ bias,
            const float* __restrict__ bias2, const void* __restrict__ resid,
            void* __restrict__ C, void* __restrict__ C2, void* __restrict__ C3,
            int M, int N, int K, int lda, int ldc)
{
    constexpr int WM = BM / 2, WN = BN / 2, RM = WM / 16, RN = WN / 16;
    __shared__ __align__(16) bf16_t As0[BM * 64], As1[BM * 64];
    __shared__ __align__(16) bf16_t Bs0[BN * 64], Bs1[BN * 64];

    const int t = threadIdx.x;
    const int lane = t & 63, wave = t >> 6;
    int bx = blockIdx.x, by = blockIdx.y;
    xcd_remap(bx, by, gridDim.x, gridDim.y);
    const int m0 = by * BM, n0 = bx * BN;
    const int wm = (wave & 1) * WM, wn = (wave >> 1) * WN;
    const int fr = lane & 15, quad = lane >> 4;

    // staging lane geometry: each wave-instruction covers 8 rows (1024B)
    const int lr = lane >> 3;               // row within 8-row chunk
    const int kof = ((lane & 7) ^ lr) * 8;  // inverse-swizzled K element offset

    const bf16_t* A1b = A1;
    if (CMODE == 6) A1b = A1 + (n0 >= 768 ? (long)4096 * 768 : 0);

    f32x4 acc[RM][RN];
#pragma unroll
    for (int i = 0; i < RM; i++)
#pragma unroll
        for (int j = 0; j < RN; j++)
#pragma unroll
            for (int p = 0; p < 4; p++) acc[i][j][p] = 0.f;

    auto stage = [&](bf16_t* As, bf16_t* Bs, int kt) {
        const bf16_t* Ab = A0;
        int kk = kt;
        if (CONCAT && kt >= 768) { Ab = A1b; kk = kt - 768; }
        const bf16_t* asrc = Ab + (long)(m0 + wave * 8 + lr) * lda + kk + kof;
#pragma unroll
        for (int c = 0; c < BM / 32; ++c)
            gload16(asrc + (long)c * 32 * lda, &As[(c * 32 + wave * 8) * 64]);
        const bf16_t* bsrc = Bt + (long)(n0 + wave * 8 + lr) * K + kt + kof;
#pragma unroll
        for (int c = 0; c < BN / 32; ++c)
            gload16(bsrc + (long)c * 32 * K, &Bs[(c * 32 + wave * 8) * 64]);
    };

    const int sw = fr & 7;
    auto compute = [&](const bf16_t* As, const bf16_t* Bs) {
        bf16x8v af[RM][2], bfr[RN][2];
        const int s0 = quad ^ sw;
#pragma unroll
        for (int i = 0; i < RM; ++i) {
            const char* rb = (const char*)As + (wm + i * 16 + fr) * 128;
            af[i][0] = *(const bf16x8v*)(rb + (s0 << 4));
            af[i][1] = *(const bf16x8v*)(rb + ((s0 ^ 4) << 4));
        }
#pragma unroll
        for (int j = 0; j < RN; ++j) {
            const char* rb = (const char*)Bs + (wn + j * 16 + fr) * 128;
            bfr[j][0] = *(const bf16x8v*)(rb + (s0 << 4));
            bfr[j][1] = *(const bf16x8v*)(rb + ((s0 ^ 4) << 4));
        }
#pragma unroll
        for (int ks = 0; ks < 2; ++ks)
#pragma unroll
            for (int i = 0; i < RM; ++i)
#pragma unroll
                for (int j = 0; j < RN; ++j)
                    acc[i][j] = __builtin_amdgcn_mfma_f32_16x16x32_bf16(af[i][ks], bfr[j][ks], acc[i][j], 0, 0, 0);
    };

    const int nk = K >> 6;   // even for all shapes used (K % 128 == 0)
    stage(As0, Bs0, 0);
    __syncthreads();
    for (int kt = 0; kt + 2 <= nk; kt += 2) {
        stage(As1, Bs1, (kt + 1) << 6);
        compute(As0, Bs0);
        __syncthreads();
        if (kt + 2 < nk) stage(As0, Bs0, (kt + 2) << 6);
        compute(As1, Bs1);
        __syncthreads();
    }

    const int rq = quad * 4, cn = fr;
#pragma unroll
    for (int i = 0; i < RM; i++)
#pragma unroll
        for (int j = 0; j < RN; j++) {
            int col = n0 + wn + j * 16 + cn;
            int t3 = (CMODE == 4 || CMODE == 5 || CMODE == 9) ? (col / 768) : 0;
            int cc = col - t3 * 768;
            float bv = 0.f;
            if (CMODE == 5)      bv = t3 ? bias2[cc] : bias[cc];
            else if (CMODE == 6) bv = (col < 768) ? bias[col] : bias2[col - 768];
            else if (bias)       bv = bias[col];
            const int row0 = m0 + wm + i * 16 + rq;
            float vv[4];
#pragma unroll
            for (int p = 0; p < 4; p++) {
                float v = acc[i][j][p] + bv;
                if (ACT == 1) v = 1.f / (1.f + __expf(-v));
                if (ACT == 2) {   // 0.5*(1+tanh(u)) == sigmoid(2u), exact
                    float u2 = 1.5957691216057308f * (v + 0.044715f * v * v * v);
                    v = v / (1.f + __expf(-u2));
                }
                if (RES == 2) v += ((const float*)resid)[(long)(row0 + p) * ldc + col];
                vv[p] = v;
            }
            if (CMODE == 0) {
#pragma unroll
                for (int p = 0; p < 4; p++) {
                    long idx = (long)(row0 + p) * ldc + col;
                    if (OUT == 0)      ((bf16_t*)C)[idx] = (bf16_t)vv[p];
                    else if (OUT == 1) ((float*)C)[idx] = vv[p];
                    else { ((float*)C)[idx] = vv[p]; ((bf16_t*)C2)[idx] = (bf16_t)vv[p]; }
                }
            } else if (CMODE == 6) {
                long base = (col < 768) ? 0 : ((long)4096 * 768 - 768);
#pragma unroll
                for (int p = 0; p < 4; p++)
                    ((bf16_t*)C)[base + (long)(row0 + p) * 768 + col] = (bf16_t)vv[p];
            } else if (CMODE == 7) {
#pragma unroll
                for (int p = 0; p < 4; p++) {
                    long idx = (long)(row0 + p) * ldc + col;
                    float a  = (float)((const bf16_t*)C2)[idx];
                    float a1 = (float)((const bf16_t*)C3)[idx];
                    ((bf16_t*)C)[idx] = (bf16_t)(vv[p] * a + (1.f - vv[p]) * a1);
                }
            } else if (CMODE == 9) {
                // mem repack fused: row = slot (zero slots >= 100); cc in [0,768)
                int hh = cc >> 6, dd = cc & 63;
                if (t3 == 0) {
#pragma unroll
                    for (int p = 0; p < 4; p++)
                        ((bf16_t*)C)[(long)hh * 8192 + (row0 + p) * 64 + dd] =
                            (row0 + p < 100) ? (bf16_t)vv[p] : (bf16_t)0.f;
                } else {
                    union { ushort4 u4; bf16_t b[4]; } pk;
#pragma unroll
                    for (int p = 0; p < 4; p++)
                        pk.b[p] = (row0 + p < 100) ? (bf16_t)vv[p] : (bf16_t)0.f;
                    *(ushort4*)((bf16_t*)C2 + (long)hh * 8192 + dd * 128 + row0) = pk.u4;
                }
            } else {
                int bb = row0 >> 10, ss0 = row0 & 1023;
                int hh = cc >> 6, dd = cc & 63;
                long srow = (long)(bb * CH + hh) * 1024 + ss0;     // *64+dd per p
                long tbase = (((long)(bb * CH + hh) * 64) + dd) * 1024 + ss0;
                union { ushort4 u4; bf16_t b[4]; } pk;
#pragma unroll
                for (int p = 0; p < 4; p++) pk.b[p] = (bf16_t)vv[p];
                if (CMODE == 2) {
#pragma unroll
                    for (int p = 0; p < 4; p++)
                        ((bf16_t*)C)[(srow + p) * 64 + dd] = pk.b[p];
                } else if (CMODE == 5) {
                    if (t3 == 0) {
#pragma unroll
                        for (int p = 0; p < 4; p++)
                            ((bf16_t*)C)[(srow + p) * 64 + dd] = pk.b[p];
                    } else {
                        *(ushort4*)((bf16_t*)C2 + tbase) = pk.u4;   // 4 consecutive s
                    }
                } else {   // CMODE 4
                    if (t3 == 0) {
#pragma unroll
                        for (int p = 0; p < 4; p++)
                            ((bf16_t*)C)[(srow + p) * 64 + dd] = pk.b[p];
                    } else if (t3 == 1) {
#pragma unroll
                        for (int p = 0; p < 4; p++)
                            ((bf16_t*)C2)[(srow + p) * 64 + dd] = pk.b[p];
                    } else {
                        *(ushort4*)((bf16_t*)C3 + tbase) = pk.u4;
                    }
                }
            }
        }
}

// ===== fused flash attention, D=64, QR-row Q tiles, 64-wide key tiles =====
// SWAPPED QK^T: s = mfma(K, Q); lane holds q-row P slices; Q/P/K/V share the
// XOR slot swizzle; Q staged via global_load_lds. K AND V double-buffered:
// ONE barrier per key tile ({stage t+1 | qkt_sm(t) | pv(t) | barrier} — pv
// reads wave-private Ps + V(t) which landed at the previous barrier).
// lrow kept as PER-LANE partial (alpha-scaled), reduced once in the epilogue.
// MODE 1: enc, BOTH encoders (gridDim.z=96, e=z/48), scale 1/8, key mask.
// MODE 3: COMBINED self+memory: z<48 self (Sk=1024), z>=48 memory via K2/V2
//         (Sk=128 padded, valid 100, out +SZel). Scale 1 (log2e folded).
template<int MODE, int QR>
__global__ __launch_bounds__(256)
void flash_attn(const bf16_t* __restrict__ Q, const bf16_t* __restrict__ K,
                const bf16_t* __restrict__ V, const bf16_t* __restrict__ K2,
                const bf16_t* __restrict__ V2, const int* __restrict__ mask,
                bf16_t* __restrict__ O)
{
    constexpr int QG = QR / 64;            // q-row groups per wave
    __shared__ __align__(16) bf16_t Qs[QR * 64];   // swizzled; reused as P strips
    __shared__ __align__(16) bf16_t Ks0[64 * 64], Ks1[64 * 64];
    __shared__ __align__(16) bf16_t Vs0[64 * 64], Vs1[64 * 64];

    const int t = threadIdx.x;
    const int lane = t & 63, wave = t >> 6;
    int bx = blockIdx.x, bz = blockIdx.z;
    {   // XCD remap over (x,z): co-locate blocks sharing K/V on one XCD L2
        int nwg = gridDim.x * gridDim.z;
        if ((nwg & 7) == 0) {
            int lin = bz * gridDim.x + bx;
            int lin2 = (lin & 7) * (nwg >> 3) + (lin >> 3);
            bx = lin2 % gridDim.x;
            bz = lin2 / gridDim.x;
        }
    }
    const bool memrole = (MODE == 3) && (bz >= 48);
    const int zq = (MODE == 1) ? (bz % 48) : (memrole ? bz - 48 : bz);
    const int b = zq / CH, h = zq % CH;
    long obase = (MODE == 1) ? (long)(bz / 48) * ((long)4096 * 768)
                             : (memrole ? (long)4096 * 768 : 0);
    const int q0 = bx * QR;

    const bf16_t* Qb = Q + (long)zq * 65536 + (long)q0 * 64;
    const bf16_t* Kb = memrole ? K2 + (long)h * 8192 : K + (long)bz * 65536;
    const bf16_t* Vb = memrole ? V2 + (long)h * 8192 : V + (long)bz * 65536;
    const int ldv = memrole ? 128 : 1024;
    const int NT = memrole ? 2 : 16;
    // log2-domain scale folded into Q fragment: exp(s*c) == exp2(s*c*log2e)
    constexpr float SCL = (MODE == 1) ? 0.18033688011112042f : 1.4426950408889634f;

    const int lr = lane >> 3, kof = ((lane & 7) ^ lr) * 8;

    auto stageK = [&](bf16_t* Ks, int kt) {
#pragma unroll
        for (int c = 0; c < 2; ++c) {
            int r = wave * 8 + c * 32;
            gload16(Kb + (long)(kt * 64 + r + lr) * 64 + kof, &Ks[r * 64]);
        }
    };
    auto stageV = [&](bf16_t* Vs, int kt) {
#pragma unroll
        for (int c = 0; c < 2; ++c) {
            int r = wave * 8 + c * 32;
            gload16(Vb + (long)(r + lr) * ldv + kt * 64 + kof, &Vs[r * 64]);
        }
    };

    stageK(Ks0, 0);
    stageV(Vs0, 0);
#pragma unroll
    for (int c = 0; c < QR / 32; ++c) {   // Q staged like K (swizzled source)
        int r = wave * 8 + c * 32;
        gload16(Qb + (long)(r + lr) * 64 + kof, &Qs[r * 64]);
    }
    __syncthreads();   // Q + K/V tile 0 landed

    const int fr = lane & 15, quad = lane >> 4;
    const int sw = fr & 7;
    bf16x8v qf[QG][2];
#pragma unroll
    for (int g = 0; g < QG; g++)
#pragma unroll
        for (int ks = 0; ks < 2; ks++) {
            const char* rb = (const char*)Qs + (wave * (16 * QG) + g * 16 + fr) * 128;
            bf16x8v raw = *(const bf16x8v*)(rb + (((quad ^ sw) ^ (ks << 2)) << 4));
#pragma unroll
            for (int i = 0; i < 8; i++) qf[g][ks][i] = (bf16_t)((float)raw[i] * SCL);
        }

    bf16_t* Ps = &Qs[wave * (16 * QG) * 64];

    f32x4 o[4][QG];
    float mrow[QG], lrow[QG];   // lrow = per-lane partial (reduced at epilogue)
#pragma unroll
    for (int g = 0; g < QG; g++) { mrow[g] = -1e30f; lrow[g] = 0.f; }
#pragma unroll
    for (int j = 0; j < 4; j++)
#pragma unroll
        for (int g = 0; g < QG; g++)
#pragma unroll
            for (int p = 0; p < 4; p++) o[j][g][p] = 0.f;

    auto qkt_sm = [&](const bf16_t* Ks, int kt) {
        f32x4 s[4][QG];
#pragma unroll
        for (int j = 0; j < 4; j++)
#pragma unroll
            for (int g = 0; g < QG; g++)
#pragma unroll
                for (int p = 0; p < 4; p++) s[j][g][p] = 0.f;
        __builtin_amdgcn_s_setprio(1);
#pragma unroll
        for (int ks = 0; ks < 2; ks++) {
            bf16x8v bk[4];
#pragma unroll
            for (int j = 0; j < 4; j++) {
                const char* rb = (const char*)Ks + (j * 16 + fr) * 128;
                bk[j] = *(const bf16x8v*)(rb + (((quad ^ sw) ^ (ks << 2)) << 4));
            }
#pragma unroll
            for (int j = 0; j < 4; j++)   // SWAPPED: K as A, Q as B
#pragma unroll
                for (int g = 0; g < QG; g++)
                    s[j][g] = __builtin_amdgcn_mfma_f32_16x16x32_bf16(bk[j], qf[g][ks], s[j][g], 0, 0, 0);
        }
        __builtin_amdgcn_s_setprio(0);
        // s[j][g][p]: key = kt*64 + j*16 + quad*4 + p, q-row = g*16 + fr
        if (MODE == 1) {
#pragma unroll
            for (int j = 0; j < 4; j++) {
                int4 mv = *(const int4*)&mask[(long)b * 1024 + kt * 64 + j * 16 + quad * 4];
#pragma unroll
                for (int g = 0; g < QG; g++) {
                    s[j][g][0] = mv.x ? -14426.95f : s[j][g][0];
                    s[j][g][1] = mv.y ? -14426.95f : s[j][g][1];
                    s[j][g][2] = mv.z ? -14426.95f : s[j][g][2];
                    s[j][g][3] = mv.w ? -14426.95f : s[j][g][3];
                }
            }
        }
        if (MODE == 3 && memrole) {
#pragma unroll
            for (int j = 0; j < 4; j++)
#pragma unroll
                for (int p = 0; p < 4; p++)
                    if (kt * 64 + j * 16 + quad * 4 + p >= 100)
#pragma unroll
                        for (int g = 0; g < QG; g++) s[j][g][p] = -1e30f;
        }
        float tmax[QG];
        bool need = false;
#pragma unroll
        for (int g = 0; g < QG; g++) {
            float tm = s[0][g][0];
#pragma unroll
            for (int j = 0; j < 4; j++)
#pragma unroll
                for (int p = 0; p < 4; p++) tm = fmaxf(tm, s[j][g][p]);
            tm = fmaxf(tm, __shfl_xor(tm, 16, 64));
            tm = fmaxf(tm, __shfl_xor(tm, 32, 64));
            tmax[g] = tm;
            need = need || (tm > mrow[g] + 8.f);
        }
        if (__any(need ? 1 : 0)) {   // rescale (skipped when maxes stable)
#pragma unroll
            for (int g = 0; g < QG; g++) {
                float mnew = fmaxf(mrow[g], tmax[g]);
                float alpha = fexp2(mrow[g] - mnew);
                lrow[g] *= alpha;
                mrow[g] = mnew;
                float arow[4];
#pragma unroll
                for (int p = 0; p < 4; p++)
                    arow[p] = __shfl(alpha, (lane & 48) | (quad * 4 + p), 64);
#pragma unroll
                for (int j = 0; j < 4; j++)
#pragma unroll
                    for (int p = 0; p < 4; p++) o[j][g][p] *= arow[p];
            }
        }
#pragma unroll
        for (int g = 0; g < QG; g++) {
            float rs = 0.f;
#pragma unroll
            for (int j = 0; j < 4; j++)
#pragma unroll
                for (int p = 0; p < 4; p++) {
                    float e = fexp2(s[j][g][p] - mrow[g]);   // bounded by 2^8
                    s[j][g][p] = e;
                    rs += e;
                }
            lrow[g] += rs;   // per-lane partial; cross-quad reduce at epilogue
        }
        // P -> A-layout (swizzled): keys quad*4+p consecutive -> packed b64
#pragma unroll
        for (int j = 0; j < 4; j++)
#pragma unroll
            for (int g = 0; g < QG; g++) {
                union { uint2 u; bf16_t bb[4]; } pk;
#pragma unroll
                for (int p = 0; p < 4; p++) pk.bb[p] = (bf16_t)s[j][g][p];
                int row = g * 16 + fr;
                *(uint2*)((char*)Ps + row * 128 +
                          (((j * 2 + (quad >> 1)) ^ sw) << 4) + ((quad & 1) << 3)) = pk.u;
            }
    };

    auto pv = [&](const bf16_t* Vs) {
        __builtin_amdgcn_s_setprio(1);
#pragma unroll
        for (int ks = 0; ks < 2; ks++) {
            bf16x8v af[QG], bv[4];
#pragma unroll
            for (int g = 0; g < QG; g++) {
                const char* rb = (const char*)Ps + (g * 16 + fr) * 128;
                af[g] = *(const bf16x8v*)(rb + (((quad ^ sw) ^ (ks << 2)) << 4));
            }
#pragma unroll
            for (int j = 0; j < 4; j++) {
                const char* rb = (const char*)Vs + (j * 16 + fr) * 128;
                bv[j] = *(const bf16x8v*)(rb + (((quad ^ sw) ^ (ks << 2)) << 4));
            }
#pragma unroll
            for (int j = 0; j < 4; j++)
#pragma unroll
                for (int g = 0; g < QG; g++)
                    o[j][g] = __builtin_amdgcn_mfma_f32_16x16x32_bf16(af[g], bv[j], o[j][g], 0, 0, 0);
        }
        __builtin_amdgcn_s_setprio(0);
    };

    for (int kt = 0; kt < NT; kt += 2) {   // ONE barrier per key tile
        if (kt + 1 < NT) { stageK(Ks1, kt + 1); stageV(Vs1, kt + 1); }
        qkt_sm(Ks0, kt);
        pv(Vs0);
        __syncthreads();   // drains prefetch; all waves done with Ks0/Vs0
        if (kt + 2 < NT) { stageK(Ks0, kt + 2); stageV(Vs0, kt + 2); }
        qkt_sm(Ks1, kt + 1);
        pv(Vs1);
        __syncthreads();
    }
    // o[j][g][p]: q-row = g*16 + quad*4 + p (wave-local), out dim = j*16+fr
#pragma unroll
    for (int g = 0; g < QG; g++) {
        lrow[g] += __shfl_xor(lrow[g], 16, 64);   // deferred cross-quad sum
        lrow[g] += __shfl_xor(lrow[g], 32, 64);
        float linv[4];
#pragma unroll
        for (int p = 0; p < 4; p++)
            linv[p] = 1.f / __shfl(lrow[g], (lane & 48) | (quad * 4 + p), 64);
#pragma unroll
        for (int p = 0; p < 4; p++) {
            int srow = q0 + wave * (16 * QG) + g * 16 + quad * 4 + p;
            long base = ((long)b * 1024 + srow) * 768 + h * 64 + obase;
#pragma unroll
            for (int j = 0; j < 4; j++)
                O[base + j * 16 + fr] = (bf16_t)(o[j][g][p] * linv[p]);
        }
    }
}

// ===== LayerNorm rows of 768 (f32 in, bf16 out) =====
__device__ __forceinline__ void ln_vals(float v0, float v1, float v2, bf16_t* out,
                                        const float* g, const float* b,
                                        long ob, int t)
{
    __shared__ float red[4];
    float s = v0 + v1 + v2;
    for (int m = 32; m; m >>= 1) s += __shfl_xor(s, m, 64);
    if ((t & 63) == 0) red[t >> 6] = s;
    __syncthreads();
    s = red[0] + red[1] + red[2] + red[3];
    __syncthreads();
    const float mu = s * (1.f / 768.f);
    float d0 = v0 - mu, d1 = v1 - mu, d2 = v2 - mu;
    float q = d0 * d0 + d1 * d1 + d2 * d2;
    for (int m = 32; m; m >>= 1) q += __shfl_xor(q, m, 64);
    if ((t & 63) == 0) red[t >> 6] = q;
    __syncthreads();
    q = red[0] + red[1] + red[2] + red[3];
    const float rstd = rsqrtf(q * (1.f / 768.f) + 1e-5f);
    out[ob + t]       = (bf16_t)(g[t]       * d0 * rstd + b[t]);
    out[ob + t + 256] = (bf16_t)(g[t + 256] * d1 * rstd + b[t + 256]);
    out[ob + t + 512] = (bf16_t)(g[t + 512] * d2 * rstd + b[t + 512]);
}

__global__ __launch_bounds__(256)
void ln_kernel(const float* __restrict__ in, bf16_t* __restrict__ out,
               const float* __restrict__ g, const float* __restrict__ b)
{
    const int r = blockIdx.x;
    const int t = threadIdx.x;
    long base = (long)r * CE;
    ln_vals(in[base + t], in[base + t + 256], in[base + t + 512],
            out, g, b, base, t);
}

// LN1(residf) -> outA  (blocks 0..4095)  AND  ln_enc(encf) -> outB (4096..12287)
__global__ __launch_bounds__(256)
void ln_both(const float* __restrict__ residf, const float* __restrict__ encf,
             bf16_t* __restrict__ outA, bf16_t* __restrict__ outB,
             const float* __restrict__ g, const float* __restrict__ b)
{
    const int r = blockIdx.x, t = threadIdx.x;
    if (r < 4096) {
        long base = (long)r * CE;
        ln_vals(residf[base + t], residf[base + t + 256], residf[base + t + 512],
                outA, g, b, base, t);
    } else {
        const int rr = r - 4096;
        const int e = rr >> 12, r2 = rr & 4095, bb = r2 >> 10, s = r2 & 1023;
        long base = ((long)(bb * 2 + e) * 1024 + s) * CE;
        ln_vals(encf[base + t], encf[base + t + 256], encf[base + t + 512],
                outB, g, b, (long)rr * CE, t);
    }
}

// gate-blend of the two encoder paths + residual + LN2, all in one kernel:
// v = g1*r + (1-g1)*e1 + g2*r + (1-g2)*e2, *= 1/sqrt2; rf = v; out = LN(v).
__global__ __launch_bounds__(256)
void fuse_gates_ln(const bf16_t* __restrict__ gal, const bf16_t* __restrict__ eo,
                   float* __restrict__ rf, bf16_t* __restrict__ out,
                   const float* __restrict__ g, const float* __restrict__ b)
{
    const long SZel = (long)4096 * 768;
    const int r = blockIdx.x, t = threadIdx.x;
    long base = (long)r * CE;
    float v[3];
#pragma unroll
    for (int k = 0; k < 3; k++) {
        long idx = base + t + k * 256;
        float g1 = (float)gal[idx], g2 = (float)gal[idx + SZel];
        float e1 = (float)eo[idx],  e2 = (float)eo[idx + SZel];
        float rr = rf[idx];
        float vv = (g1 * rr + (1.f - g1) * e1 + g2 * rr + (1.f - g2) * e2)
                   * 0.7071067811865476f;
        rf[idx] = vv;
        v[k] = vv;
    }
    ln_vals(v[0], v[1], v[2], out, g, b, base, t);
}

__global__ void zero_out(float* __restrict__ out)
{
    out[blockIdx.x * 256 + threadIdx.x] = 0.f;
}

// ===== batched weight transpose+cast (12 weights) + mem pad-cast, ONE dispatch =====
#define NTW 12
struct TTab {
    const float* src[NTW];
    unsigned long dst[NTW];   // byte offset into ws
    int kn[NTW];              // K<<16 | N
    int pre[NTW + 1];         // tile prefix sums
    const float* memf;        // pad-cast source [100,768]
    unsigned long membOff;    // pad-cast dest (bf16 [128,768])
};

__global__ void transpose_all(TTab tt, char* __restrict__ ws)
{
    __shared__ bf16_t tile[32][33];
    int tb = blockIdx.x;
    if (tb >= tt.pre[NTW]) {   // pad-cast slab: 384 blocks x 256 elems
        int idx = (tb - tt.pre[NTW]) * 256 + threadIdx.y * 32 + threadIdx.x;
        int row = idx / 768;
        ((bf16_t*)(ws + tt.membOff))[idx] =
            (row < 100) ? (bf16_t)tt.memf[idx] : (bf16_t)0.f;
        return;
    }
    int e = 0;
#pragma unroll
    for (int i = 0; i < NTW; i++) if (tb >= tt.pre[i + 1]) e = i + 1;
    int local = tb - tt.pre[e];
    const int K = tt.kn[e] >> 16, N = tt.kn[e] & 0xffff;
    const float* in = tt.src[e];
    bf16_t* out = (bf16_t*)(ws + tt.dst[e]);
    const int ntx = N / 32;
    const int n0 = (local % ntx) * 32, k0 = (local / ntx) * 32;
    int tx = threadIdx.x, ty = threadIdx.y;
    for (int i = ty; i < 32; i += 8)
        tile[i][tx] = (bf16_t)in[(long)(k0 + i) * N + n0 + tx];
    __syncthreads();
    for (int i = ty; i < 32; i += 8)
        out[(long)(n0 + i) * K + k0 + tx] = tile[tx][i];
}

// ===================================================================================
extern "C" void kernel_launch(void* const* d_in, const int* in_sizes, int n_in,
                              void* d_out, int out_size, void* d_ws, size_t ws_size,
                              hipStream_t stream)
{
    (void)in_sizes; (void)n_in; (void)out_size;
    const float* x        = (const float*)d_in[0];
    const float* encf     = (const float*)d_in[1];
    const int*   maskenc  = (const int*)d_in[2];
    const float* ln1_g    = (const float*)d_in[3];
    const float* ln1_b    = (const float*)d_in[4];
    const float* ln2_g    = (const float*)d_in[5];
    const float* ln2_b    = (const float*)d_in[6];
    const float* c_attn_w = (const float*)d_in[7];
    const float* c_attn_b = (const float*)d_in[8];
    const float* aproj_w  = (const float*)d_in[9];
    const float* aproj_b  = (const float*)d_in[10];
    const float* memf     = (const float*)d_in[11];
    const float* mattn_w  = (const float*)d_in[12];
    const float* mattn_b  = (const float*)d_in[13];
    const float* malpha_w = (const float*)d_in[14];
    const float* malpha_b = (const float*)d_in[15];
    const float* fcq_w    = (const float*)d_in[16];
    const float* fcq_b    = (const float*)d_in[17];
    const float* fck_w    = (const float*)d_in[18];
    const float* fck_b    = (const float*)d_in[19];
    const float* fcv_w    = (const float*)d_in[20];
    const float* fcv_b    = (const float*)d_in[21];
    const float* eproj_w  = (const float*)d_in[22];
    const float* eproj_b  = (const float*)d_in[23];
    const float* fa1_w    = (const float*)d_in[24];
    const float* fa1_b    = (const float*)d_in[25];
    const float* fa2_w    = (const float*)d_in[26];
    const float* fa2_b    = (const float*)d_in[27];
    const float* mfc_w    = (const float*)d_in[28];
    const float* mfc_b    = (const float*)d_in[29];
    const float* mproj_w  = (const float*)d_in[30];
    const float* mproj_b  = (const float*)d_in[31];
    float* dout = (float*)d_out;

    size_t off = 0;
    auto alloc = [&](size_t bytes) -> void* {
        void* p = (char*)d_ws + off;
        off = (off + bytes + 255) & ~(size_t)255;
        return p;
    };
    const size_t SZ = (size_t)4096 * 768 * 2;
    const long SZel = (long)4096 * 768;
    bf16_t* wt_cattn  = (bf16_t*)alloc((size_t)2304 * 768 * 2);
    bf16_t* wt_aproj  = (bf16_t*)alloc((size_t)768 * 768 * 2);
    bf16_t* wt_malpha = (bf16_t*)alloc((size_t)768 * 1536 * 2);
    bf16_t* wt_fcq    = (bf16_t*)alloc((size_t)768 * 768 * 2);
    bf16_t* wt_fck    = (bf16_t*)alloc((size_t)768 * 768 * 2);   // adjacent:
    bf16_t* wt_fcv    = (bf16_t*)alloc((size_t)768 * 768 * 2);   // wt_fck..wt_fcv = [1536,768]
    bf16_t* wt_eproj  = (bf16_t*)alloc((size_t)768 * 768 * 2);
    bf16_t* wt_fa1    = (bf16_t*)alloc((size_t)768 * 1536 * 2);  // adjacent:
    bf16_t* wt_fa2    = (bf16_t*)alloc((size_t)768 * 1536 * 2);  // wt_fa1..wt_fa2 = [1536,1536]
    bf16_t* wt_mfc    = (bf16_t*)alloc((size_t)3072 * 768 * 2);
    bf16_t* wt_mproj  = (bf16_t*)alloc((size_t)768 * 3072 * 2);
    bf16_t* wt_mattn  = (bf16_t*)alloc((size_t)1536 * 768 * 2);
    bf16_t* memb   = (bf16_t*)alloc((size_t)128 * 768 * 2);   // padded bf16 memf
    bf16_t* mkt    = (bf16_t*)alloc((size_t)CH * 128 * 64 * 2);
    bf16_t* mvt    = (bf16_t*)alloc((size_t)CH * 64 * 128 * 2);
    bf16_t* bufA   = (bf16_t*)alloc(SZ);        // LN out [4096,768] / blended attn
    bf16_t* qbuf   = (bf16_t*)alloc(SZ);        // q [4,12,1024,64]
    bf16_t* kbuf   = (bf16_t*)alloc(2 * SZ);    // k [2|4,12,1024,64] / gates / mid lo
    bf16_t* vtbuf  = (bf16_t*)alloc(2 * SZ);    // v [2|4,12,64,1024] / mid hi
    bf16_t* asbuf  = (bf16_t*)alloc(2 * SZ);    // attn out: self[0]+mem[1] / enc e0,e1
    bf16_t* bufB   = (bf16_t*)alloc(2 * SZ);    // enc LN [8192,768] / eproj out
    float*  residf = (float*)alloc((size_t)4096 * 768 * 4);
    bf16_t* residb = (bf16_t*)alloc(SZ);        // bf16 copy of residual (A for fa gates)

    if (off > ws_size) {   // finite diagnostic
        zero_out<<<12288, 256, 0, stream>>>(dout);
        return;
    }
    bf16_t* mid = kbuf;          // [4096,3072] spans kbuf+vtbuf (both dead at MLP)
    bf16_t* galbuf = kbuf;       // stacked gate outputs [8192,768] (dead k)
    bf16_t* eobuf = bufB;        // stacked eproj outputs [8192,768]

    const dim3 blk(256);

    // ---- batched transpose table + mem pad-cast (one dispatch) ----
    TTab tt;
    {
        const float* srcs[NTW] = {c_attn_w, aproj_w, malpha_w, fcq_w, fck_w, fcv_w,
                                  eproj_w, fa1_w, fa2_w, mfc_w, mproj_w, mattn_w};
        bf16_t* dsts[NTW] = {wt_cattn, wt_aproj, wt_malpha, wt_fcq, wt_fck, wt_fcv,
                             wt_eproj, wt_fa1, wt_fa2, wt_mfc, wt_mproj, wt_mattn};
        int Ks[NTW] = {768, 768, 1536, 768, 768, 768, 768, 1536, 1536, 768, 3072, 768};
        int Ns[NTW] = {2304, 768, 768, 768, 768, 768, 768, 768, 768, 3072, 768, 1536};
        int acc = 0;
        for (int i = 0; i < NTW; i++) {
            tt.src[i] = srcs[i];
            tt.dst[i] = (unsigned long)((char*)dsts[i] - (char*)d_ws);
            tt.kn[i] = (Ks[i] << 16) | Ns[i];
            tt.pre[i] = acc;
            acc += (Ks[i] / 32) * (Ns[i] / 32);
        }
        tt.pre[NTW] = acc;
        tt.memf = memf;
        tt.membOff = (unsigned long)((char*)memb - (char*)d_ws);
        transpose_all<<<acc + 384, dim3(32, 8), 0, stream>>>(tt, (char*)d_ws);
    }

    // memory-slot projection with FUSED repack (CMODE 9): memb -> mkt/mvt
    gemm_n<64,64,0,0,0,0,9><<<dim3(24, 2), blk, 0, stream>>>(
        memb, nullptr, wt_mattn, mattn_b, nullptr, nullptr, mkt, mvt, nullptr,
        128, 1536, 768, 768, 1536);

    // h = LN1(x); qkv with fused head split  (128x64: 48KB LDS, 3 blocks/CU)
    ln_kernel<<<4096, blk, 0, stream>>>(x, bufA, ln1_g, ln1_b);
    gemm_n<128,64,0,0,0,0,4><<<dim3(36, 32), blk, 0, stream>>>(
        bufA, nullptr, wt_cattn, c_attn_b, nullptr, nullptr, qbuf, kbuf, vtbuf,
        4096, 2304, 768, 768, 0);

    // self + memory attention in ONE dispatch (z<48 self, z>=48 memory); QR=128
    flash_attn<3,128><<<dim3(8, 1, 96), blk, 0, stream>>>(
        qbuf, kbuf, vtbuf, mkt, mvt, nullptr, asbuf);

    // memory gate with FUSED blend (CMODE 7): bufA = g*self + (1-g)*mem  (64x64: 5/CU)
    gemm_n<64,64,1,1,0,0,7><<<dim3(12, 64), blk, 0, stream>>>(
        asbuf, asbuf + SZel, wt_malpha, malpha_b, nullptr, nullptr, bufA, asbuf, asbuf + SZel,
        4096, 768, 1536, 768, 768);
    gemm_n<64,64,0,0,2,2,0><<<dim3(12, 64), blk, 0, stream>>>(
        bufA, nullptr, wt_aproj, aproj_b, nullptr, x, residf, residb, nullptr,
        4096, 768, 768, 768, 768);

    // cross attention: LN1(resid) + enc LN in ONE dispatch; q once; encs stacked
    ln_both<<<12288, blk, 0, stream>>>(residf, encf, bufA, bufB, ln1_g, ln1_b);
    gemm_n<64,64,0,0,0,0,2><<<dim3(12, 64), blk, 0, stream>>>(
        bufA, nullptr, wt_fcq, fcq_b, nullptr, nullptr, qbuf, nullptr, nullptr,
        4096, 768, 768, 768, 0);
    gemm_n<128,64,0,0,0,0,5><<<dim3(24, 64), blk, 0, stream>>>(
        bufB, nullptr, wt_fck, fck_b, fcv_b, nullptr, kbuf, vtbuf, nullptr,
        8192, 1536, 768, 768, 0);
    // both encoder attentions in ONE dispatch; QR=128 -> 768 blocks, 3/CU resident
    flash_attn<1,128><<<dim3(8, 1, 96), blk, 0, stream>>>(
        qbuf, kbuf, vtbuf, nullptr, nullptr, maskenc, asbuf);
    gemm_n<128,64,0,0,0,0,0><<<dim3(12, 64), blk, 0, stream>>>(
        asbuf, nullptr, wt_eproj, eproj_b, nullptr, nullptr, eobuf, nullptr, nullptr,
        8192, 768, 768, 768, 768);
    // merged fa1+fa2 gates: N-stacked (cols 0-767 gate1, 768-1535 gate2)
    gemm_n<128,64,1,1,0,0,6><<<dim3(24, 32), blk, 0, stream>>>(
        residb, eobuf, wt_fa1, fa1_b, fa2_b, nullptr, galbuf, nullptr, nullptr,
        4096, 1536, 1536, 768, 768);
    // gate-blend + residual + LN2 fused (writes residf AND bufA)
    fuse_gates_ln<<<4096, blk, 0, stream>>>(galbuf, eobuf, residf, bufA, ln2_g, ln2_b);

    // MLP
    gemm_n<128,64,0,2,0,0,0><<<dim3(48, 32), blk, 0, stream>>>(
        bufA, nullptr, wt_mfc, mfc_b, nullptr, nullptr, mid, nullptr, nullptr,
        4096, 3072, 768, 768, 3072);
    gemm_n<128,64,0,0,2,1,0><<<dim3(12, 32), blk, 0, stream>>>(
        mid, nullptr, wt_mproj, mproj_b, nullptr, residf, dout, nullptr, nullptr,
        4096, 768, 3072, 3072, 768);
}

// Round 12
// 531.445 us; speedup vs baseline: 1.0280x; 1.0280x over previous
//
#include <hip/hip_runtime.h>

typedef __bf16 bf16_t;
typedef __bf16 bf16x8v __attribute__((ext_vector_type(8)));
typedef float f32x4 __attribute__((ext_vector_type(4)));

#define CB 4
#define CE 768
#define CH 12
#define CD 64

// native v_exp_f32 (exp2) without touching libm (glibc macro clash with __exp2f)
__device__ __forceinline__ float fexp2(float x) { return __builtin_amdgcn_exp2f(x); }

// async global->LDS, 16B per lane; dest = wave-uniform base + lane*16 (linear)
__device__ __forceinline__ void gload16(const void* g, void* l) {
    __builtin_amdgcn_global_load_lds((const __attribute__((address_space(1))) void*)g,
                                     (__attribute__((address_space(3))) void*)l, 16, 0, 0);
}

// bijective XCD-aware remap: XCD x computes a contiguous slab of tiles
__device__ __forceinline__ void xcd_remap(int& bx, int& by, int gx, int gy) {
    int nwg = gx * gy;
    if ((nwg & 7) == 0) {
        int lin = by * gx + bx;
        int lin2 = (lin & 7) * (nwg >> 3) + (lin >> 3);
        bx = lin2 % gx;
        by = lin2 / gx;
    }
}

// ===== MFMA GEMM, B pre-transposed [N,K] bf16, BK=64 =====
// STATIC double-buffer (As0/As1,Bs0/Bs1) + global_load_lds.
// Tile policy: 128x64 (48KB LDS, 3 blocks/CU) big GEMMs; 64x64 (32KB, 5/CU) small.
// LDS slot swizzle: physical 16B-slot p of row r holds logical slot p ^ (r&7).
// CONCAT: kk<768 -> A0, kk>=768 -> A1. ACT: 0 none,1 sigmoid,2 gelu.
// RES: 0 none, 2 += f32 resid. OUT: 0 bf16, 1 f32, 2 f32->C + bf16->C2.
// CMODE: 0 normal(ldc); 2 split [b,H,s,d]; 4 qkv->C,C2,C3; 5 kv: k->C, v->C2^T;
//        6 dual-gate (N-stacked); 7 gate-blend: C = g*C2 + (1-g)*C3;
//        9 mem: k->C=mkt [h,slot,d], v->C2=mvt [h,d,slot], zero slots>=100.
template<int BM, int BN, int CONCAT, int ACT, int RES, int OUT, int CMODE>
__global__ __launch_bounds__(256)
void gemm_n(const bf16_t* __restrict__ A0, const bf16_t* __restrict__ A1,
            const bf16_t* __restrict__ Bt, const float* __restrict__ bias,
            const float* __restrict__ bias2, const void* __restrict__ resid,
            void* __restrict__ C, void* __restrict__ C2, void* __restrict__ C3,
            int M, int N, int K, int lda, int ldc)
{
    constexpr int WM = BM / 2, WN = BN / 2, RM = WM / 16, RN = WN / 16;
    __shared__ __align__(16) bf16_t As0[BM * 64], As1[BM * 64];
    __shared__ __align__(16) bf16_t Bs0[BN * 64], Bs1[BN * 64];

    const int t = threadIdx.x;
    const int lane = t & 63, wave = t >> 6;
    int bx = blockIdx.x, by = blockIdx.y;
    xcd_remap(bx, by, gridDim.x, gridDim.y);
    const int m0 = by * BM, n0 = bx * BN;
    const int wm = (wave & 1) * WM, wn = (wave >> 1) * WN;
    const int fr = lane & 15, quad = lane >> 4;

    // staging lane geometry: each wave-instruction covers 8 rows (1024B)
    const int lr = lane >> 3;               // row within 8-row chunk
    const int kof = ((lane & 7) ^ lr) * 8;  // inverse-swizzled K element offset

    const bf16_t* A1b = A1;
    if (CMODE == 6) A1b = A1 + (n0 >= 768 ? (long)4096 * 768 : 0);

    f32x4 acc[RM][RN];
#pragma unroll
    for (int i = 0; i < RM; i++)
#pragma unroll
        for (int j = 0; j < RN; j++)
#pragma unroll
            for (int p = 0; p < 4; p++) acc[i][j][p] = 0.f;

    auto stage = [&](bf16_t* As, bf16_t* Bs, int kt) {
        const bf16_t* Ab = A0;
        int kk = kt;
        if (CONCAT && kt >= 768) { Ab = A1b; kk = kt - 768; }
        const bf16_t* asrc = Ab + (long)(m0 + wave * 8 + lr) * lda + kk + kof;
#pragma unroll
        for (int c = 0; c < BM / 32; ++c)
            gload16(asrc + (long)c * 32 * lda, &As[(c * 32 + wave * 8) * 64]);
        const bf16_t* bsrc = Bt + (long)(n0 + wave * 8 + lr) * K + kt + kof;
#pragma unroll
        for (int c = 0; c < BN / 32; ++c)
            gload16(bsrc + (long)c * 32 * K, &Bs[(c * 32 + wave * 8) * 64]);
    };

    const int sw = fr & 7;
    auto compute = [&](const bf16_t* As, const bf16_t* Bs) {
        bf16x8v af[RM][2], bfr[RN][2];
        const int s0 = quad ^ sw;
#pragma unroll
        for (int i = 0; i < RM; ++i) {
            const char* rb = (const char*)As + (wm + i * 16 + fr) * 128;
            af[i][0] = *(const bf16x8v*)(rb + (s0 << 4));
            af[i][1] = *(const bf16x8v*)(rb + ((s0 ^ 4) << 4));
        }
#pragma unroll
        for (int j = 0; j < RN; ++j) {
            const char* rb = (const char*)Bs + (wn + j * 16 + fr) * 128;
            bfr[j][0] = *(const bf16x8v*)(rb + (s0 << 4));
            bfr[j][1] = *(const bf16x8v*)(rb + ((s0 ^ 4) << 4));
        }
#pragma unroll
        for (int ks = 0; ks < 2; ++ks)
#pragma unroll
            for (int i = 0; i < RM; ++i)
#pragma unroll
                for (int j = 0; j < RN; ++j)
                    acc[i][j] = __builtin_amdgcn_mfma_f32_16x16x32_bf16(af[i][ks], bfr[j][ks], acc[i][j], 0, 0, 0);
    };

    const int nk = K >> 6;   // even for all shapes used (K % 128 == 0)
    stage(As0, Bs0, 0);
    __syncthreads();
    for (int kt = 0; kt + 2 <= nk; kt += 2) {
        stage(As1, Bs1, (kt + 1) << 6);
        compute(As0, Bs0);
        __syncthreads();
        if (kt + 2 < nk) stage(As0, Bs0, (kt + 2) << 6);
        compute(As1, Bs1);
        __syncthreads();
    }

    const int rq = quad * 4, cn = fr;
#pragma unroll
    for (int i = 0; i < RM; i++)
#pragma unroll
        for (int j = 0; j < RN; j++) {
            int col = n0 + wn + j * 16 + cn;
            int t3 = (CMODE == 4 || CMODE == 5 || CMODE == 9) ? (col / 768) : 0;
            int cc = col - t3 * 768;
            float bv = 0.f;
            if (CMODE == 5)      bv = t3 ? bias2[cc] : bias[cc];
            else if (CMODE == 6) bv = (col < 768) ? bias[col] : bias2[col - 768];
            else if (bias)       bv = bias[col];
            const int row0 = m0 + wm + i * 16 + rq;
            float vv[4];
#pragma unroll
            for (int p = 0; p < 4; p++) {
                float v = acc[i][j][p] + bv;
                if (ACT == 1) v = 1.f / (1.f + __expf(-v));
                if (ACT == 2) {   // 0.5*(1+tanh(u)) == sigmoid(2u), exact
                    float u2 = 1.5957691216057308f * (v + 0.044715f * v * v * v);
                    v = v / (1.f + __expf(-u2));
                }
                if (RES == 2) v += ((const float*)resid)[(long)(row0 + p) * ldc + col];
                vv[p] = v;
            }
            if (CMODE == 0) {
#pragma unroll
                for (int p = 0; p < 4; p++) {
                    long idx = (long)(row0 + p) * ldc + col;
                    if (OUT == 0)      ((bf16_t*)C)[idx] = (bf16_t)vv[p];
                    else if (OUT == 1) ((float*)C)[idx] = vv[p];
                    else { ((float*)C)[idx] = vv[p]; ((bf16_t*)C2)[idx] = (bf16_t)vv[p]; }
                }
            } else if (CMODE == 6) {
                long base = (col < 768) ? 0 : ((long)4096 * 768 - 768);
#pragma unroll
                for (int p = 0; p < 4; p++)
                    ((bf16_t*)C)[base + (long)(row0 + p) * 768 + col] = (bf16_t)vv[p];
            } else if (CMODE == 7) {
#pragma unroll
                for (int p = 0; p < 4; p++) {
                    long idx = (long)(row0 + p) * ldc + col;
                    float a  = (float)((const bf16_t*)C2)[idx];
                    float a1 = (float)((const bf16_t*)C3)[idx];
                    ((bf16_t*)C)[idx] = (bf16_t)(vv[p] * a + (1.f - vv[p]) * a1);
                }
            } else if (CMODE == 9) {
                // mem repack fused: row = slot (zero slots >= 100); cc in [0,768)
                int hh = cc >> 6, dd = cc & 63;
                if (t3 == 0) {
#pragma unroll
                    for (int p = 0; p < 4; p++)
                        ((bf16_t*)C)[(long)hh * 8192 + (row0 + p) * 64 + dd] =
                            (row0 + p < 100) ? (bf16_t)vv[p] : (bf16_t)0.f;
                } else {
                    union { ushort4 u4; bf16_t b[4]; } pk;
#pragma unroll
                    for (int p = 0; p < 4; p++)
                        pk.b[p] = (row0 + p < 100) ? (bf16_t)vv[p] : (bf16_t)0.f;
                    *(ushort4*)((bf16_t*)C2 + (long)hh * 8192 + dd * 128 + row0) = pk.u4;
                }
            } else {
                int bb = row0 >> 10, ss0 = row0 & 1023;
                int hh = cc >> 6, dd = cc & 63;
                long srow = (long)(bb * CH + hh) * 1024 + ss0;     // *64+dd per p
                long tbase = (((long)(bb * CH + hh) * 64) + dd) * 1024 + ss0;
                union { ushort4 u4; bf16_t b[4]; } pk;
#pragma unroll
                for (int p = 0; p < 4; p++) pk.b[p] = (bf16_t)vv[p];
                if (CMODE == 2) {
#pragma unroll
                    for (int p = 0; p < 4; p++)
                        ((bf16_t*)C)[(srow + p) * 64 + dd] = pk.b[p];
                } else if (CMODE == 5) {
                    if (t3 == 0) {
#pragma unroll
                        for (int p = 0; p < 4; p++)
                            ((bf16_t*)C)[(srow + p) * 64 + dd] = pk.b[p];
                    } else {
                        *(ushort4*)((bf16_t*)C2 + tbase) = pk.u4;   // 4 consecutive s
                    }
                } else {   // CMODE 4
                    if (t3 == 0) {
#pragma unroll
                        for (int p = 0; p < 4; p++)
                            ((bf16_t*)C)[(srow + p) * 64 + dd] = pk.b[p];
                    } else if (t3 == 1) {
#pragma unroll
                        for (int p = 0; p < 4; p++)
                            ((bf16_t*)C2)[(srow + p) * 64 + dd] = pk.b[p];
                    } else {
                        *(ushort4*)((bf16_t*)C3 + tbase) = pk.u4;
                    }
                }
            }
        }
}

// ===== fused flash attention, D=64, QR-row Q tiles, 64-wide key tiles =====
// SWAPPED QK^T: s = mfma(K, Q); lane holds q-row P slices; Q/P/K/V share the
// XOR slot swizzle; Q staged via global_load_lds. K AND V double-buffered:
// ONE barrier per key tile ({stage t+1 | qkt_sm(t) | pv(t) | barrier} — pv
// reads wave-private Ps + V(t) which landed at the previous barrier).
// lrow kept as PER-LANE partial (alpha-scaled), reduced once in the epilogue.
// QR policy (measured): MODE 3 QR=64 (40KB LDS -> 4 blocks/CU; occupancy is
// the lever); MODE 1 QR=128 (48KB -> 3/CU; fewer blocks, half staging/row —
// equal perf to QR=64, keeps VGPR off the self-role critical path).
// MODE 1: enc, BOTH encoders (gridDim.z=96, e=z/48), scale 1/8, key mask.
// MODE 3: COMBINED self+memory: z<48 self (Sk=1024), z>=48 memory via K2/V2
//         (Sk=128 padded, valid 100, out +SZel). Scale 1 (log2e folded).
template<int MODE, int QR>
__global__ __launch_bounds__(256)
void flash_attn(const bf16_t* __restrict__ Q, const bf16_t* __restrict__ K,
                const bf16_t* __restrict__ V, const bf16_t* __restrict__ K2,
                const bf16_t* __restrict__ V2, const int* __restrict__ mask,
                bf16_t* __restrict__ O)
{
    constexpr int QG = QR / 64;            // q-row groups per wave
    __shared__ __align__(16) bf16_t Qs[QR * 64];   // swizzled; reused as P strips
    __shared__ __align__(16) bf16_t Ks0[64 * 64], Ks1[64 * 64];
    __shared__ __align__(16) bf16_t Vs0[64 * 64], Vs1[64 * 64];

    const int t = threadIdx.x;
    const int lane = t & 63, wave = t >> 6;
    int bx = blockIdx.x, bz = blockIdx.z;
    {   // XCD remap over (x,z): co-locate blocks sharing K/V on one XCD L2
        int nwg = gridDim.x * gridDim.z;
        if ((nwg & 7) == 0) {
            int lin = bz * gridDim.x + bx;
            int lin2 = (lin & 7) * (nwg >> 3) + (lin >> 3);
            bx = lin2 % gridDim.x;
            bz = lin2 / gridDim.x;
        }
    }
    const bool memrole = (MODE == 3) && (bz >= 48);
    const int zq = (MODE == 1) ? (bz % 48) : (memrole ? bz - 48 : bz);
    const int b = zq / CH, h = zq % CH;
    long obase = (MODE == 1) ? (long)(bz / 48) * ((long)4096 * 768)
                             : (memrole ? (long)4096 * 768 : 0);
    const int q0 = bx * QR;

    const bf16_t* Qb = Q + (long)zq * 65536 + (long)q0 * 64;
    const bf16_t* Kb = memrole ? K2 + (long)h * 8192 : K + (long)bz * 65536;
    const bf16_t* Vb = memrole ? V2 + (long)h * 8192 : V + (long)bz * 65536;
    const int ldv = memrole ? 128 : 1024;
    const int NT = memrole ? 2 : 16;
    // log2-domain scale folded into Q fragment: exp(s*c) == exp2(s*c*log2e)
    constexpr float SCL = (MODE == 1) ? 0.18033688011112042f : 1.4426950408889634f;

    const int lr = lane >> 3, kof = ((lane & 7) ^ lr) * 8;

    auto stageK = [&](bf16_t* Ks, int kt) {
#pragma unroll
        for (int c = 0; c < 2; ++c) {
            int r = wave * 8 + c * 32;
            gload16(Kb + (long)(kt * 64 + r + lr) * 64 + kof, &Ks[r * 64]);
        }
    };
    auto stageV = [&](bf16_t* Vs, int kt) {
#pragma unroll
        for (int c = 0; c < 2; ++c) {
            int r = wave * 8 + c * 32;
            gload16(Vb + (long)(r + lr) * ldv + kt * 64 + kof, &Vs[r * 64]);
        }
    };

    stageK(Ks0, 0);
    stageV(Vs0, 0);
#pragma unroll
    for (int c = 0; c < QR / 32; ++c) {   // Q staged like K (swizzled source)
        int r = wave * 8 + c * 32;
        gload16(Qb + (long)(r + lr) * 64 + kof, &Qs[r * 64]);
    }
    __syncthreads();   // Q + K/V tile 0 landed

    const int fr = lane & 15, quad = lane >> 4;
    const int sw = fr & 7;
    bf16x8v qf[QG][2];
#pragma unroll
    for (int g = 0; g < QG; g++)
#pragma unroll
        for (int ks = 0; ks < 2; ks++) {
            const char* rb = (const char*)Qs + (wave * (16 * QG) + g * 16 + fr) * 128;
            bf16x8v raw = *(const bf16x8v*)(rb + (((quad ^ sw) ^ (ks << 2)) << 4));
#pragma unroll
            for (int i = 0; i < 8; i++) qf[g][ks][i] = (bf16_t)((float)raw[i] * SCL);
        }

    bf16_t* Ps = &Qs[wave * (16 * QG) * 64];

    f32x4 o[4][QG];
    float mrow[QG], lrow[QG];   // lrow = per-lane partial (reduced at epilogue)
#pragma unroll
    for (int g = 0; g < QG; g++) { mrow[g] = -1e30f; lrow[g] = 0.f; }
#pragma unroll
    for (int j = 0; j < 4; j++)
#pragma unroll
        for (int g = 0; g < QG; g++)
#pragma unroll
            for (int p = 0; p < 4; p++) o[j][g][p] = 0.f;

    auto qkt_sm = [&](const bf16_t* Ks, int kt) {
        f32x4 s[4][QG];
#pragma unroll
        for (int j = 0; j < 4; j++)
#pragma unroll
            for (int g = 0; g < QG; g++)
#pragma unroll
                for (int p = 0; p < 4; p++) s[j][g][p] = 0.f;
        __builtin_amdgcn_s_setprio(1);
#pragma unroll
        for (int ks = 0; ks < 2; ks++) {
            bf16x8v bk[4];
#pragma unroll
            for (int j = 0; j < 4; j++) {
                const char* rb = (const char*)Ks + (j * 16 + fr) * 128;
                bk[j] = *(const bf16x8v*)(rb + (((quad ^ sw) ^ (ks << 2)) << 4));
            }
#pragma unroll
            for (int j = 0; j < 4; j++)   // SWAPPED: K as A, Q as B
#pragma unroll
                for (int g = 0; g < QG; g++)
                    s[j][g] = __builtin_amdgcn_mfma_f32_16x16x32_bf16(bk[j], qf[g][ks], s[j][g], 0, 0, 0);
        }
        __builtin_amdgcn_s_setprio(0);
        // s[j][g][p]: key = kt*64 + j*16 + quad*4 + p, q-row = g*16 + fr
        if (MODE == 1) {
#pragma unroll
            for (int j = 0; j < 4; j++) {
                int4 mv = *(const int4*)&mask[(long)b * 1024 + kt * 64 + j * 16 + quad * 4];
#pragma unroll
                for (int g = 0; g < QG; g++) {
                    s[j][g][0] = mv.x ? -14426.95f : s[j][g][0];
                    s[j][g][1] = mv.y ? -14426.95f : s[j][g][1];
                    s[j][g][2] = mv.z ? -14426.95f : s[j][g][2];
                    s[j][g][3] = mv.w ? -14426.95f : s[j][g][3];
                }
            }
        }
        if (MODE == 3 && memrole) {
#pragma unroll
            for (int j = 0; j < 4; j++)
#pragma unroll
                for (int p = 0; p < 4; p++)
                    if (kt * 64 + j * 16 + quad * 4 + p >= 100)
#pragma unroll
                        for (int g = 0; g < QG; g++) s[j][g][p] = -1e30f;
        }
        float tmax[QG];
        bool need = false;
#pragma unroll
        for (int g = 0; g < QG; g++) {
            float tm = s[0][g][0];
#pragma unroll
            for (int j = 0; j < 4; j++)
#pragma unroll
                for (int p = 0; p < 4; p++) tm = fmaxf(tm, s[j][g][p]);
            tm = fmaxf(tm, __shfl_xor(tm, 16, 64));
            tm = fmaxf(tm, __shfl_xor(tm, 32, 64));
            tmax[g] = tm;
            need = need || (tm > mrow[g] + 8.f);
        }
        if (__any(need ? 1 : 0)) {   // rescale (skipped when maxes stable)
#pragma unroll
            for (int g = 0; g < QG; g++) {
                float mnew = fmaxf(mrow[g], tmax[g]);
                float alpha = fexp2(mrow[g] - mnew);
                lrow[g] *= alpha;
                mrow[g] = mnew;
                float arow[4];
#pragma unroll
                for (int p = 0; p < 4; p++)
                    arow[p] = __shfl(alpha, (lane & 48) | (quad * 4 + p), 64);
#pragma unroll
                for (int j = 0; j < 4; j++)
#pragma unroll
                    for (int p = 0; p < 4; p++) o[j][g][p] *= arow[p];
            }
        }
#pragma unroll
        for (int g = 0; g < QG; g++) {
            float rs = 0.f;
#pragma unroll
            for (int j = 0; j < 4; j++)
#pragma unroll
                for (int p = 0; p < 4; p++) {
                    float e = fexp2(s[j][g][p] - mrow[g]);   // bounded by 2^8
                    s[j][g][p] = e;
                    rs += e;
                }
            lrow[g] += rs;   // per-lane partial; cross-quad reduce at epilogue
        }
        // P -> A-layout (swizzled): keys quad*4+p consecutive -> packed b64
#pragma unroll
        for (int j = 0; j < 4; j++)
#pragma unroll
            for (int g = 0; g < QG; g++) {
                union { uint2 u; bf16_t bb[4]; } pk;
#pragma unroll
                for (int p = 0; p < 4; p++) pk.bb[p] = (bf16_t)s[j][g][p];
                int row = g * 16 + fr;
                *(uint2*)((char*)Ps + row * 128 +
                          (((j * 2 + (quad >> 1)) ^ sw) << 4) + ((quad & 1) << 3)) = pk.u;
            }
    };

    auto pv = [&](const bf16_t* Vs) {
        __builtin_amdgcn_s_setprio(1);
#pragma unroll
        for (int ks = 0; ks < 2; ks++) {
            bf16x8v af[QG], bv[4];
#pragma unroll
            for (int g = 0; g < QG; g++) {
                const char* rb = (const char*)Ps + (g * 16 + fr) * 128;
                af[g] = *(const bf16x8v*)(rb + (((quad ^ sw) ^ (ks << 2)) << 4));
            }
#pragma unroll
            for (int j = 0; j < 4; j++) {
                const char* rb = (const char*)Vs + (j * 16 + fr) * 128;
                bv[j] = *(const bf16x8v*)(rb + (((quad ^ sw) ^ (ks << 2)) << 4));
            }
#pragma unroll
            for (int j = 0; j < 4; j++)
#pragma unroll
                for (int g = 0; g < QG; g++)
                    o[j][g] = __builtin_amdgcn_mfma_f32_16x16x32_bf16(af[g], bv[j], o[j][g], 0, 0, 0);
        }
        __builtin_amdgcn_s_setprio(0);
    };

    for (int kt = 0; kt < NT; kt += 2) {   // ONE barrier per key tile
        if (kt + 1 < NT) { stageK(Ks1, kt + 1); stageV(Vs1, kt + 1); }
        qkt_sm(Ks0, kt);
        pv(Vs0);
        __syncthreads();   // drains prefetch; all waves done with Ks0/Vs0
        if (kt + 2 < NT) { stageK(Ks0, kt + 2); stageV(Vs0, kt + 2); }
        qkt_sm(Ks1, kt + 1);
        pv(Vs1);
        __syncthreads();
    }
    // o[j][g][p]: q-row = g*16 + quad*4 + p (wave-local), out dim = j*16+fr
#pragma unroll
    for (int g = 0; g < QG; g++) {
        lrow[g] += __shfl_xor(lrow[g], 16, 64);   // deferred cross-quad sum
        lrow[g] += __shfl_xor(lrow[g], 32, 64);
        float linv[4];
#pragma unroll
        for (int p = 0; p < 4; p++)
            linv[p] = 1.f / __shfl(lrow[g], (lane & 48) | (quad * 4 + p), 64);
#pragma unroll
        for (int p = 0; p < 4; p++) {
            int srow = q0 + wave * (16 * QG) + g * 16 + quad * 4 + p;
            long base = ((long)b * 1024 + srow) * 768 + h * 64 + obase;
#pragma unroll
            for (int j = 0; j < 4; j++)
                O[base + j * 16 + fr] = (bf16_t)(o[j][g][p] * linv[p]);
        }
    }
}

// ===== LayerNorm rows of 768 (f32 in, bf16 out) =====
__device__ __forceinline__ void ln_vals(float v0, float v1, float v2, bf16_t* out,
                                        const float* g, const float* b,
                                        long ob, int t)
{
    __shared__ float red[4];
    float s = v0 + v1 + v2;
    for (int m = 32; m; m >>= 1) s += __shfl_xor(s, m, 64);
    if ((t & 63) == 0) red[t >> 6] = s;
    __syncthreads();
    s = red[0] + red[1] + red[2] + red[3];
    __syncthreads();
    const float mu = s * (1.f / 768.f);
    float d0 = v0 - mu, d1 = v1 - mu, d2 = v2 - mu;
    float q = d0 * d0 + d1 * d1 + d2 * d2;
    for (int m = 32; m; m >>= 1) q += __shfl_xor(q, m, 64);
    if ((t & 63) == 0) red[t >> 6] = q;
    __syncthreads();
    q = red[0] + red[1] + red[2] + red[3];
    const float rstd = rsqrtf(q * (1.f / 768.f) + 1e-5f);
    out[ob + t]       = (bf16_t)(g[t]       * d0 * rstd + b[t]);
    out[ob + t + 256] = (bf16_t)(g[t + 256] * d1 * rstd + b[t + 256]);
    out[ob + t + 512] = (bf16_t)(g[t + 512] * d2 * rstd + b[t + 512]);
}

__global__ __launch_bounds__(256)
void ln_kernel(const float* __restrict__ in, bf16_t* __restrict__ out,
               const float* __restrict__ g, const float* __restrict__ b)
{
    const int r = blockIdx.x;
    const int t = threadIdx.x;
    long base = (long)r * CE;
    ln_vals(in[base + t], in[base + t + 256], in[base + t + 512],
            out, g, b, base, t);
}

// LN1(residf) -> outA  (blocks 0..4095)  AND  ln_enc(encf) -> outB (4096..12287)
__global__ __launch_bounds__(256)
void ln_both(const float* __restrict__ residf, const float* __restrict__ encf,
             bf16_t* __restrict__ outA, bf16_t* __restrict__ outB,
             const float* __restrict__ g, const float* __restrict__ b)
{
    const int r = blockIdx.x, t = threadIdx.x;
    if (r < 4096) {
        long base = (long)r * CE;
        ln_vals(residf[base + t], residf[base + t + 256], residf[base + t + 512],
                outA, g, b, base, t);
    } else {
        const int rr = r - 4096;
        const int e = rr >> 12, r2 = rr & 4095, bb = r2 >> 10, s = r2 & 1023;
        long base = ((long)(bb * 2 + e) * 1024 + s) * CE;
        ln_vals(encf[base + t], encf[base + t + 256], encf[base + t + 512],
                outB, g, b, (long)rr * CE, t);
    }
}

// gate-blend of the two encoder paths + residual + LN2, all in one kernel:
// v = g1*r + (1-g1)*e1 + g2*r + (1-g2)*e2, *= 1/sqrt2; rf = v; out = LN(v).
__global__ __launch_bounds__(256)
void fuse_gates_ln(const bf16_t* __restrict__ gal, const bf16_t* __restrict__ eo,
                   float* __restrict__ rf, bf16_t* __restrict__ out,
                   const float* __restrict__ g, const float* __restrict__ b)
{
    const long SZel = (long)4096 * 768;
    const int r = blockIdx.x, t = threadIdx.x;
    long base = (long)r * CE;
    float v[3];
#pragma unroll
    for (int k = 0; k < 3; k++) {
        long idx = base + t + k * 256;
        float g1 = (float)gal[idx], g2 = (float)gal[idx + SZel];
        float e1 = (float)eo[idx],  e2 = (float)eo[idx + SZel];
        float rr = rf[idx];
        float vv = (g1 * rr + (1.f - g1) * e1 + g2 * rr + (1.f - g2) * e2)
                   * 0.7071067811865476f;
        rf[idx] = vv;
        v[k] = vv;
    }
    ln_vals(v[0], v[1], v[2], out, g, b, base, t);
}

__global__ void zero_out(float* __restrict__ out)
{
    out[blockIdx.x * 256 + threadIdx.x] = 0.f;
}

// ===== batched weight transpose+cast (12 weights) + mem pad-cast, ONE dispatch =====
#define NTW 12
struct TTab {
    const float* src[NTW];
    unsigned long dst[NTW];   // byte offset into ws
    int kn[NTW];              // K<<16 | N
    int pre[NTW + 1];         // tile prefix sums
    const float* memf;        // pad-cast source [100,768]
    unsigned long membOff;    // pad-cast dest (bf16 [128,768])
};

__global__ void transpose_all(TTab tt, char* __restrict__ ws)
{
    __shared__ bf16_t tile[32][33];
    int tb = blockIdx.x;
    if (tb >= tt.pre[NTW]) {   // pad-cast slab: 384 blocks x 256 elems
        int idx = (tb - tt.pre[NTW]) * 256 + threadIdx.y * 32 + threadIdx.x;
        int row = idx / 768;
        ((bf16_t*)(ws + tt.membOff))[idx] =
            (row < 100) ? (bf16_t)tt.memf[idx] : (bf16_t)0.f;
        return;
    }
    int e = 0;
#pragma unroll
    for (int i = 0; i < NTW; i++) if (tb >= tt.pre[i + 1]) e = i + 1;
    int local = tb - tt.pre[e];
    const int K = tt.kn[e] >> 16, N = tt.kn[e] & 0xffff;
    const float* in = tt.src[e];
    bf16_t* out = (bf16_t*)(ws + tt.dst[e]);
    const int ntx = N / 32;
    const int n0 = (local % ntx) * 32, k0 = (local / ntx) * 32;
    int tx = threadIdx.x, ty = threadIdx.y;
    for (int i = ty; i < 32; i += 8)
        tile[i][tx] = (bf16_t)in[(long)(k0 + i) * N + n0 + tx];
    __syncthreads();
    for (int i = ty; i < 32; i += 8)
        out[(long)(n0 + i) * K + k0 + tx] = tile[tx][i];
}

// ===================================================================================
extern "C" void kernel_launch(void* const* d_in, const int* in_sizes, int n_in,
                              void* d_out, int out_size, void* d_ws, size_t ws_size,
                              hipStream_t stream)
{
    (void)in_sizes; (void)n_in; (void)out_size;
    const float* x        = (const float*)d_in[0];
    const float* encf     = (const float*)d_in[1];
    const int*   maskenc  = (const int*)d_in[2];
    const float* ln1_g    = (const float*)d_in[3];
    const float* ln1_b    = (const float*)d_in[4];
    const float* ln2_g    = (const float*)d_in[5];
    const float* ln2_b    = (const float*)d_in[6];
    const float* c_attn_w = (const float*)d_in[7];
    const float* c_attn_b = (const float*)d_in[8];
    const float* aproj_w  = (const float*)d_in[9];
    const float* aproj_b  = (const float*)d_in[10];
    const float* memf     = (const float*)d_in[11];
    const float* mattn_w  = (const float*)d_in[12];
    const float* mattn_b  = (const float*)d_in[13];
    const float* malpha_w = (const float*)d_in[14];
    const float* malpha_b = (const float*)d_in[15];
    const float* fcq_w    = (const float*)d_in[16];
    const float* fcq_b    = (const float*)d_in[17];
    const float* fck_w    = (const float*)d_in[18];
    const float* fck_b    = (const float*)d_in[19];
    const float* fcv_w    = (const float*)d_in[20];
    const float* fcv_b    = (const float*)d_in[21];
    const float* eproj_w  = (const float*)d_in[22];
    const float* eproj_b  = (const float*)d_in[23];
    const float* fa1_w    = (const float*)d_in[24];
    const float* fa1_b    = (const float*)d_in[25];
    const float* fa2_w    = (const float*)d_in[26];
    const float* fa2_b    = (const float*)d_in[27];
    const float* mfc_w    = (const float*)d_in[28];
    const float* mfc_b    = (const float*)d_in[29];
    const float* mproj_w  = (const float*)d_in[30];
    const float* mproj_b  = (const float*)d_in[31];
    float* dout = (float*)d_out;

    size_t off = 0;
    auto alloc = [&](size_t bytes) -> void* {
        void* p = (char*)d_ws + off;
        off = (off + bytes + 255) & ~(size_t)255;
        return p;
    };
    const size_t SZ = (size_t)4096 * 768 * 2;
    const long SZel = (long)4096 * 768;
    bf16_t* wt_cattn  = (bf16_t*)alloc((size_t)2304 * 768 * 2);
    bf16_t* wt_aproj  = (bf16_t*)alloc((size_t)768 * 768 * 2);
    bf16_t* wt_malpha = (bf16_t*)alloc((size_t)768 * 1536 * 2);
    bf16_t* wt_fcq    = (bf16_t*)alloc((size_t)768 * 768 * 2);
    bf16_t* wt_fck    = (bf16_t*)alloc((size_t)768 * 768 * 2);   // adjacent:
    bf16_t* wt_fcv    = (bf16_t*)alloc((size_t)768 * 768 * 2);   // wt_fck..wt_fcv = [1536,768]
    bf16_t* wt_eproj  = (bf16_t*)alloc((size_t)768 * 768 * 2);
    bf16_t* wt_fa1    = (bf16_t*)alloc((size_t)768 * 1536 * 2);  // adjacent:
    bf16_t* wt_fa2    = (bf16_t*)alloc((size_t)768 * 1536 * 2);  // wt_fa1..wt_fa2 = [1536,1536]
    bf16_t* wt_mfc    = (bf16_t*)alloc((size_t)3072 * 768 * 2);
    bf16_t* wt_mproj  = (bf16_t*)alloc((size_t)768 * 3072 * 2);
    bf16_t* wt_mattn  = (bf16_t*)alloc((size_t)1536 * 768 * 2);
    bf16_t* memb   = (bf16_t*)alloc((size_t)128 * 768 * 2);   // padded bf16 memf
    bf16_t* mkt    = (bf16_t*)alloc((size_t)CH * 128 * 64 * 2);
    bf16_t* mvt    = (bf16_t*)alloc((size_t)CH * 64 * 128 * 2);
    bf16_t* bufA   = (bf16_t*)alloc(SZ);        // LN out [4096,768] / blended attn
    bf16_t* qbuf   = (bf16_t*)alloc(SZ);        // q [4,12,1024,64]
    bf16_t* kbuf   = (bf16_t*)alloc(2 * SZ);    // k [2|4,12,1024,64] / gates / mid lo
    bf16_t* vtbuf  = (bf16_t*)alloc(2 * SZ);    // v [2|4,12,64,1024] / mid hi
    bf16_t* asbuf  = (bf16_t*)alloc(2 * SZ);    // attn out: self[0]+mem[1] / enc e0,e1
    bf16_t* bufB   = (bf16_t*)alloc(2 * SZ);    // enc LN [8192,768] / eproj out
    float*  residf = (float*)alloc((size_t)4096 * 768 * 4);
    bf16_t* residb = (bf16_t*)alloc(SZ);        // bf16 copy of residual (A for fa gates)

    if (off > ws_size) {   // finite diagnostic
        zero_out<<<12288, 256, 0, stream>>>(dout);
        return;
    }
    bf16_t* mid = kbuf;          // [4096,3072] spans kbuf+vtbuf (both dead at MLP)
    bf16_t* galbuf = kbuf;       // stacked gate outputs [8192,768] (dead k)
    bf16_t* eobuf = bufB;        // stacked eproj outputs [8192,768]

    const dim3 blk(256);

    // ---- batched transpose table + mem pad-cast (one dispatch) ----
    TTab tt;
    {
        const float* srcs[NTW] = {c_attn_w, aproj_w, malpha_w, fcq_w, fck_w, fcv_w,
                                  eproj_w, fa1_w, fa2_w, mfc_w, mproj_w, mattn_w};
        bf16_t* dsts[NTW] = {wt_cattn, wt_aproj, wt_malpha, wt_fcq, wt_fck, wt_fcv,
                             wt_eproj, wt_fa1, wt_fa2, wt_mfc, wt_mproj, wt_mattn};
        int Ks[NTW] = {768, 768, 1536, 768, 768, 768, 768, 1536, 1536, 768, 3072, 768};
        int Ns[NTW] = {2304, 768, 768, 768, 768, 768, 768, 768, 768, 3072, 768, 1536};
        int acc = 0;
        for (int i = 0; i < NTW; i++) {
            tt.src[i] = srcs[i];
            tt.dst[i] = (unsigned long)((char*)dsts[i] - (char*)d_ws);
            tt.kn[i] = (Ks[i] << 16) | Ns[i];
            tt.pre[i] = acc;
            acc += (Ks[i] / 32) * (Ns[i] / 32);
        }
        tt.pre[NTW] = acc;
        tt.memf = memf;
        tt.membOff = (unsigned long)((char*)memb - (char*)d_ws);
        transpose_all<<<acc + 384, dim3(32, 8), 0, stream>>>(tt, (char*)d_ws);
    }

    // memory-slot projection with FUSED repack (CMODE 9): memb -> mkt/mvt
    gemm_n<64,64,0,0,0,0,9><<<dim3(24, 2), blk, 0, stream>>>(
        memb, nullptr, wt_mattn, mattn_b, nullptr, nullptr, mkt, mvt, nullptr,
        128, 1536, 768, 768, 1536);

    // h = LN1(x); qkv with fused head split  (128x64: 48KB LDS, 3 blocks/CU)
    ln_kernel<<<4096, blk, 0, stream>>>(x, bufA, ln1_g, ln1_b);
    gemm_n<128,64,0,0,0,0,4><<<dim3(36, 32), blk, 0, stream>>>(
        bufA, nullptr, wt_cattn, c_attn_b, nullptr, nullptr, qbuf, kbuf, vtbuf,
        4096, 2304, 768, 768, 0);

    // self + memory attention in ONE dispatch (z<48 self, z>=48 memory); QR=64
    flash_attn<3,64><<<dim3(16, 1, 96), blk, 0, stream>>>(
        qbuf, kbuf, vtbuf, mkt, mvt, nullptr, asbuf);

    // memory gate with FUSED blend (CMODE 7): bufA = g*self + (1-g)*mem  (64x64: 5/CU)
    gemm_n<64,64,1,1,0,0,7><<<dim3(12, 64), blk, 0, stream>>>(
        asbuf, asbuf + SZel, wt_malpha, malpha_b, nullptr, nullptr, bufA, asbuf, asbuf + SZel,
        4096, 768, 1536, 768, 768);
    gemm_n<64,64,0,0,2,2,0><<<dim3(12, 64), blk, 0, stream>>>(
        bufA, nullptr, wt_aproj, aproj_b, nullptr, x, residf, residb, nullptr,
        4096, 768, 768, 768, 768);

    // cross attention: LN1(resid) + enc LN in ONE dispatch; q once; encs stacked
    ln_both<<<12288, blk, 0, stream>>>(residf, encf, bufA, bufB, ln1_g, ln1_b);
    gemm_n<64,64,0,0,0,0,2><<<dim3(12, 64), blk, 0, stream>>>(
        bufA, nullptr, wt_fcq, fcq_b, nullptr, nullptr, qbuf, nullptr, nullptr,
        4096, 768, 768, 768, 0);
    gemm_n<128,64,0,0,0,0,5><<<dim3(24, 64), blk, 0, stream>>>(
        bufB, nullptr, wt_fck, fck_b, fcv_b, nullptr, kbuf, vtbuf, nullptr,
        8192, 1536, 768, 768, 0);
    // both encoder attentions in ONE dispatch; QR=128 -> 768 blocks, 3/CU resident
    flash_attn<1,128><<<dim3(8, 1, 96), blk, 0, stream>>>(
        qbuf, kbuf, vtbuf, nullptr, nullptr, maskenc, asbuf);
    gemm_n<128,64,0,0,0,0,0><<<dim3(12, 64), blk, 0, stream>>>(
        asbuf, nullptr, wt_eproj, eproj_b, nullptr, nullptr, eobuf, nullptr, nullptr,
        8192, 768, 768, 768, 768);
    // merged fa1+fa2 gates: N-stacked (cols 0-767 gate1, 768-1535 gate2)
    gemm_n<128,64,1,1,0,0,6><<<dim3(24, 32), blk, 0, stream>>>(
        residb, eobuf, wt_fa1, fa1_b, fa2_b, nullptr, galbuf, nullptr, nullptr,
        4096, 1536, 1536, 768, 768);
    // gate-blend + residual + LN2 fused (writes residf AND bufA)
    fuse_gates_ln<<<4096, blk, 0, stream>>>(galbuf, eobuf, residf, bufA, ln2_g, ln2_b);

    // MLP
    gemm_n<128,64,0,2,0,0,0><<<dim3(48, 32), blk, 0, stream>>>(
        bufA, nullptr, wt_mfc, mfc_b, nullptr, nullptr, mid, nullptr, nullptr,
        4096, 3072, 768, 768, 3072);
    gemm_n<128,64,0,0,2,1,0><<<dim3(12, 32), blk, 0, stream>>>(
        mid, nullptr, wt_mproj, mproj_b, nullptr, residf, dout, nullptr, nullptr,
        4096, 768, 3072, 3072, 768);
}